// Round 3
// baseline (242.441 us; speedup 1.0000x reference)
//
#include <hip/hip_runtime.h>
#include <hip/hip_bf16.h>
#include <cmath>

#define S_LEN 2048
#define DMODEL 1024
#define NHEADS 16
#define DK 64
#define BATCH 2
#define MTOT (BATCH * S_LEN) /* 4096 */

using short8 = __attribute__((ext_vector_type(8))) short;
using floatx4 = __attribute__((ext_vector_type(4))) float;

// float -> bf16 bits, round-to-nearest-even (scalar path)
__device__ __forceinline__ unsigned short f2b(float f) {
    union { float f; unsigned u; } v; v.f = f;
    unsigned r = v.u + 0x7fff + ((v.u >> 16) & 1);
    return (unsigned short)(r >> 16);
}

// packed 2x float -> bf16x2 (v_cvt_pk_bf16_f32)
__device__ __forceinline__ unsigned pack2(float a, float b) {
    float2 t; t.x = a; t.y = b;
    __hip_bfloat162 h = __float22bfloat162_rn(t);
    union { __hip_bfloat162 h; unsigned u; } v; v.h = h;
    return v.u;
}

// async global->LDS, 16 B/lane. LDS dest is wave-uniform base (+lane*16 by HW).
__device__ __forceinline__ void gload16(const void* g, void* l) {
    __builtin_amdgcn_global_load_lds(
        (const __attribute__((address_space(1))) unsigned int*)g,
        (__attribute__((address_space(3))) unsigned int*)l, 16, 0, 0);
}

#define FENCE() asm volatile("" ::: "memory")

// ---------------------------------------------------------------------------
// Fused preprocessing (single dispatch, blockIdx-range partition):
//   blocks [0, 2048)        : x fp32 -> bf16 cast
//   blocks [2048, 2304)     : RoPE cos/sin tables
//   blocks [2304, 3328)     : W fp32 [k][n] -> bf16 [n][k] transpose
//                             (Wq,Wk head-dims permuted: d -> d/2 or 32+d/2)
// ---------------------------------------------------------------------------
__global__ __launch_bounds__(256) void prep_k(
    const float* __restrict__ x, unsigned short* __restrict__ xb,
    const int* __restrict__ tokpos, float* __restrict__ ct, float* __restrict__ st,
    const float* W0, const float* W1, const float* W2, const float* W3,
    unsigned short* T0, unsigned short* T1, unsigned short* T2, unsigned short* T3) {
    __shared__ float t[64][65];
    const int b = blockIdx.x;
    if (b < 2048) {
        int i = (b * 256 + threadIdx.x) * 8;
        float4 a = *(const float4*)(x + i);
        float4 bb = *(const float4*)(x + i + 4);
        short8 o;
        o[0] = f2b(a.x); o[1] = f2b(a.y); o[2] = f2b(a.z); o[3] = f2b(a.w);
        o[4] = f2b(bb.x); o[5] = f2b(bb.y); o[6] = f2b(bb.z); o[7] = f2b(bb.w);
        *(short8*)(xb + i) = o;
    } else if (b < 2304) {
        int idx = (b - 2048) * 256 + threadIdx.x;  // 0 .. 2048*32-1
        int si = idx >> 5;
        int ip = idx & 31;
        float pos = (float)tokpos[si];
        float inv_freq = powf(10000.0f, -(float)(2 * ip) / 64.0f);
        float ang = pos * inv_freq;
        ct[idx] = cosf(ang);
        st[idx] = sinf(ang);
    } else {
        int id = b - 2304;          // 0..1023
        int z = id >> 8;            // matrix
        int bx = id & 15, by = (id >> 4) & 15;
        const float* W = z == 0 ? W0 : z == 1 ? W1 : z == 2 ? W2 : W3;
        unsigned short* T = z == 0 ? T0 : z == 1 ? T1 : z == 2 ? T2 : T3;
        const bool perm = (z < 2);
        int n0 = bx * 64, k0 = by * 64;
        int rr = threadIdx.x >> 6, cc = threadIdx.x & 63;
#pragma unroll
        for (int r = 0; r < 16; r++) {
            int row = r * 4 + rr;
            t[row][cc] = W[(size_t)(k0 + row) * DMODEL + n0 + cc];
        }
        __syncthreads();
#pragma unroll
        for (int r = 0; r < 16; r++) {
            int row = r * 4 + rr;  // original col within head
            int drow = perm ? (((row & 1) ? 32 : 0) + (row >> 1)) : row;
            T[(size_t)(n0 + drow) * DMODEL + k0 + cc] = f2b(t[cc][row]);
        }
    }
}

// ---------------------------------------------------------------------------
// zero fp32 buffer (16 MB): 4096 blocks x 256 thr x 1 float4
// ---------------------------------------------------------------------------
__global__ __launch_bounds__(256) void zero_k(float* __restrict__ p) {
    int i = (blockIdx.x * 256 + threadIdx.x) * 4;
    *(float4*)(p + i) = (float4){0.f, 0.f, 0.f, 0.f};
}

// ---------------------------------------------------------------------------
// V[s][d] bf16 -> Vt[b*1024 + d][s] bf16, 64x64 LDS tiles
// ---------------------------------------------------------------------------
__global__ __launch_bounds__(256) void vtrans_k(const unsigned short* __restrict__ V,
                                                unsigned short* __restrict__ Vt) {
    __shared__ unsigned short t[64][72];  // 144 B rows: 16B-aligned, bank-spread
    const int tid = threadIdx.x;
    const int s0 = blockIdx.x * 64, d0 = blockIdx.y * 64;
    const int bb = s0 >> 11;
#pragma unroll
    for (int it = 0; it < 4; it++) {
        int e = (it * 256 + tid) * 4;  // flat ushort4 id: row=s, col=d
        int r = e >> 6, c = e & 63;
        *(ushort4*)&t[r][c] = *(const ushort4*)(V + (size_t)(s0 + r) * DMODEL + d0 + c);
    }
    __syncthreads();
#pragma unroll
    for (int it = 0; it < 4; it++) {
        int e = (it * 256 + tid) * 4;  // flat ushort4 id: row=d, col=s
        int r = e >> 6, c = e & 63;
        ushort4 v;
        v.x = t[c + 0][r]; v.y = t[c + 1][r];
        v.z = t[c + 2][r]; v.w = t[c + 3][r];
        *(ushort4*)(Vt + (size_t)(bb * 1024 + d0 + r) * S_LEN + (s0 & (S_LEN - 1)) + c) = v;
    }
}

// ---------------------------------------------------------------------------
// bf16 MFMA GEMM, 256x256 tile, BK=64, 8 waves (2M x 4N), 8-phase schedule
// with COUNTED vmcnt (T3+T4) + setprio (T5).
// R3: K-range parameterized (t0, NT K-tiles) for split-K.
//   kind 0: z selects matrix (Q/K/V), full K (t0=0, NT=16). RoPE/bf16
//     epilogues as before.
//   kind 1 (Wo): z = K-quarter (t0=4z, NT=4), grid (16,4,4)=256 blocks
//     (full chip vs 64 before); fp32 epilogue is unsafeAtomicAdd into the
//     pre-zeroed output (each address hit by exactly 4 blocks).
// Rotation/vmcnt invariants hold for any NT>=3: prologue 6 halves ->
// vmcnt(4) leaves h4,h5 in flight; per-K-tile vmcnt(4); drain-0 at t==NT-2.
// ---------------------------------------------------------------------------
__global__ __launch_bounds__(512, 2) void mm_k(
    const unsigned short* __restrict__ A,
    const unsigned short* __restrict__ Bt0, const unsigned short* __restrict__ Bt1,
    const unsigned short* __restrict__ Bt2,
    void* C0, void* C1, void* C2,
    const float* __restrict__ ct, const float* __restrict__ st, int kind) {
    __shared__ __align__(16) unsigned short blob[10 * 8192];  // 160 KiB

    const int z = blockIdx.z;
    const unsigned short* Bt = (kind == 1) ? Bt0 : (z == 0 ? Bt0 : z == 1 ? Bt1 : Bt2);
    void* C = (kind == 1) ? C0 : (z == 0 ? C0 : z == 1 ? C1 : C2);
    const int mode = (kind == 1) ? 0 : (z == 2 ? 3 : 1);
    const int t0 = (kind == 1) ? z * 4 : 0;   // starting K-tile
    const int NT = (kind == 1) ? 4 : 16;      // K-tiles this block
    // 0.125/ln2: QK^T scaling + exp2-domain softmax, folded into Q
    const float qscale = (z == 0 && kind == 0) ? 0.18033688011112042f : 1.0f;

    const int tid = threadIdx.x;
    const int w = tid >> 6, lane = tid & 63;
    const int l15 = lane & 15, quad = lane >> 4;
    const int wr = w >> 2, wc = w & 3;  // 2 x 4 waves; per-wave out 128x64
    const int m0 = blockIdx.x * 256, n0 = blockIdx.y * 256;  // x=m: XCD A-reuse

    // staging: per half-tile (16KB = 16 groups of 1KB), wave w owns groups
    // {w, w+8}: rows rbase / rbase+64 of the 128-row half, k-half (w&1).
    const int rbase = (w >> 1) * 16 + l15;
    const int cbase = (w & 1) * 32 + quad * 8;

    floatx4 acc[8][4];
#pragma unroll
    for (int i = 0; i < 8; i++)
#pragma unroll
        for (int j = 0; j < 4; j++) acc[i][j] = (floatx4){0.f, 0.f, 0.f, 0.f};

    auto stage_half = [&](int h) {   // h relative: K-tile t0 + (h>>2)
        const int ts = t0 + (h >> 2), part = h & 3;
        const int slot = h % 10;
        const unsigned short* src =
            (part < 2 ? A + (((size_t)(m0 + part * 128 + rbase)) << 10)
                      : Bt + (((size_t)(n0 + (part - 2) * 128 + rbase)) << 10))
            + (size_t)ts * 64 + cbase;
        char* d = (char*)blob + slot * 16384 + w * 1024;
        gload16(src, d);                       // group w   (rows rbase)
        gload16(src + (64 << 10), d + 8192);   // group w+8 (rows rbase+64)
    };

    // prologue: 6 half-tiles issued; vmcnt(4) -> K-tile t0 (h0..3) landed,
    // h4,h5 still in flight.
#pragma unroll
    for (int h = 0; h < 6; ++h) stage_half(h);
    asm volatile("s_waitcnt vmcnt(4)" ::: "memory");
    FENCE(); __builtin_amdgcn_s_barrier(); FENCE();

    short8 af[4][2];
    for (int t = 0; t < NT; ++t) {
        const int sb = (4 * t) % 10;
        int sA = sb + wr;            if (sA >= 10) sA -= 10;
        int sB = sb + 2 + (wc >> 1); if (sB >= 10) sB -= 10;
        const char* LA = (const char*)blob + sA * 16384;
        const char* LB = (const char*)blob + sB * 16384;
#pragma unroll
        for (int q = 0; q < 4; ++q) {
            const int rh = q >> 1, ch = q & 1;
            if (ch == 0) {  // A-frags for this row-half (reused next phase)
#pragma unroll
                for (int ii = 0; ii < 4; ++ii)
#pragma unroll
                    for (int kh = 0; kh < 2; ++kh)
                        af[ii][kh] = *(const short8*)(LA + ((rh * 4 + ii) * 2 + kh) * 1024 + lane * 16);
            }
            short8 bf[2][2];
#pragma unroll
            for (int jj = 0; jj < 2; ++jj)
#pragma unroll
                for (int kh = 0; kh < 2; ++kh)
                    bf[jj][kh] = *(const short8*)(LB + (((wc & 1) * 4 + ch * 2 + jj) * 2 + kh) * 1024 + lane * 16);
            const int h = 4 * t + q + 6;
            if (h < 4 * NT) stage_half(h);
            if (q == 3) {
                if (t == NT - 2) asm volatile("s_waitcnt vmcnt(0)" ::: "memory");  // tail drain
                else             asm volatile("s_waitcnt vmcnt(4)" ::: "memory");  // counted
            }
            FENCE(); __builtin_amdgcn_s_barrier(); FENCE();
            __builtin_amdgcn_s_setprio(1);
#pragma unroll
            for (int ii = 0; ii < 4; ++ii)
#pragma unroll
                for (int jj = 0; jj < 2; ++jj) {
                    floatx4 a0 = acc[rh * 4 + ii][ch * 2 + jj];
                    a0 = __builtin_amdgcn_mfma_f32_16x16x32_bf16(af[ii][0], bf[jj][0], a0, 0, 0, 0);
                    a0 = __builtin_amdgcn_mfma_f32_16x16x32_bf16(af[ii][1], bf[jj][1], a0, 0, 0, 0);
                    acc[rh * 4 + ii][ch * 2 + jj] = a0;
                }
            __builtin_amdgcn_s_setprio(0);
            FENCE(); __builtin_amdgcn_s_barrier(); FENCE();
        }
    }

    // epilogue: C/D layout col = l15, row = quad*4 + reg
#pragma unroll
    for (int i = 0; i < 8; i++) {
        const int rowb = m0 + wr * 128 + i * 16 + quad * 4;
        if (mode == 0) {
            float* Cf = (float*)C;
#pragma unroll
            for (int j = 0; j < 4; j++) {
                int colb = n0 + wc * 64 + j * 16 + l15;
#pragma unroll
                for (int r = 0; r < 4; r++)
                    unsafeAtomicAdd(&Cf[(size_t)(rowb + r) * DMODEL + colb], acc[i][j][r]);
            }
        } else if (mode == 1) {
            unsigned short* Cb = (unsigned short*)C;
#pragma unroll
            for (int jh = 0; jh < 2; jh++) {
                int ip = jh * 16 + l15;                   // pair index within head
                int cole = n0 + wc * 64 + jh * 16 + l15;  // even-member column (d'<32)
#pragma unroll
                for (int r = 0; r < 4; r++) {
                    int row = rowb + r;
                    int si = row & (S_LEN - 1);
                    float c = ct[si * 32 + ip] * qscale;
                    float s = st[si * 32 + ip] * qscale;
                    float e = acc[i][jh][r];       // x_even (permuted weights)
                    float od = acc[i][jh + 2][r];  // x_odd (partner col, same thread)
                    Cb[(size_t)row * DMODEL + cole] = f2b(e * c - od * s);
                    Cb[(size_t)row * DMODEL + cole + 32] = f2b(e * s + od * c);
                }
            }
        } else {
            unsigned short* Cb = (unsigned short*)C;
#pragma unroll
            for (int j = 0; j < 4; j++) {
                int colb = n0 + wc * 64 + j * 16 + l15;
#pragma unroll
                for (int r = 0; r < 4; r++)
                    Cb[(size_t)(rowb + r) * DMODEL + colb] = f2b(acc[i][j][r]);
            }
        }
    }
}

// ---------------------------------------------------------------------------
// Block-cooperative MFMA flash attention, 64-key tiles, 128-query blocks.
// (R1 version, reverted: R2's 3-slot rotation + shortest-last dispatch order
// regressed 53.5 -> 67.2 us; the block-order tail starvation was the cost.)
// Grid 512 = (16 q-tiles x 32 bh), longest first; 8 waves (512 thr), each
// wave owns 16 queries. One staged K/V tile feeds 8 waves. Double-buffered
// LDS via global_load_lds, 1 barrier per tile. Q pre-scaled by 0.125/ln2 ->
// exp2-domain online softmax. Wave-uniform causal fast path on interior
// tiles. Packed bf16 cvt for P/O.
// ---------------------------------------------------------------------------
__global__ __launch_bounds__(512) void attn_k(const unsigned short* __restrict__ Q,
                                              const unsigned short* __restrict__ K,
                                              const unsigned short* __restrict__ Vt,
                                              unsigned short* __restrict__ O) {
    __shared__ __align__(16) unsigned short Kblob[2][4096];  // 8 KB/buf
    __shared__ __align__(16) unsigned short Vblob[2][4096];
    __shared__ __align__(16) unsigned short Ps[8][16 * 72];  // per-wave P / O-bounce

    const int tid = threadIdx.x;
    const int w = tid >> 6, lane = tid & 63;
    const int l15 = lane & 15, quad = lane >> 4;
    const int idx = blockIdx.x;
    const int qt = 15 - (idx >> 5);  // longest blocks dispatch first
    const int bh = idx & 31;
    const int bb = bh >> 4, h = bh & 15;
    const int qbase = qt * 128 + w * 16;
    const int qrow = qbase + l15;

    // Q fragment (B-operand: col=query=l15, k=quad*8), d-halves 0/1
    const size_t qoff = (size_t)(bb * S_LEN + qbase + l15) * DMODEL + h * DK;
    short8 aq0 = *(const short8*)(Q + qoff + quad * 8);
    short8 aq1 = *(const short8*)(Q + qoff + 32 + quad * 8);

    floatx4 o[4];
#pragma unroll
    for (int f = 0; f < 4; f++) o[f] = (floatx4){0.f, 0.f, 0.f, 0.f};
    float mv = -1e30f, lv = 0.f;

    const unsigned short* Kb = K + (size_t)(bb * S_LEN) * DMODEL + h * DK;
    const unsigned short* Vb = Vt + (size_t)(bb * 1024 + h * DK) * S_LEN;
    unsigned short* ps = &Ps[w][0];

    // stage 64-key K/V tile into blob buffer b (2 gload16/thread, 8 waves)
    auto stage = [&](int b, int kb) {
#pragma unroll
        for (int it = 0; it < 2; it++) {
            int g = it * 8 + w;  // wave-uniform 0..15; 0..7 K-groups, 8..15 V-groups
            if (g < 8) {
                const unsigned short* gp =
                    Kb + (size_t)(kb + (g >> 1) * 16 + l15) * DMODEL + (g & 1) * 32 + quad * 8;
                gload16(gp, (char*)&Kblob[b][0] + g * 1024);
            } else {
                int gv = g - 8;
                const unsigned short* gp =
                    Vb + (size_t)((gv >> 1) * 16 + l15) * S_LEN + kb + (gv & 1) * 32 + quad * 8;
                gload16(gp, (char*)&Vblob[b][0] + gv * 1024);
            }
        }
    };

    const int nkt = 2 * qt + 2;  // key tiles covering 0..qt*128+127, uniform
    stage(0, 0);
    for (int kt = 0; kt < nkt; kt++) {
        const int b = kt & 1;
        const int kb = kt * 64;
        __syncthreads();  // staging of buf b complete; buf b^1 reads done
        if (kt + 1 < nkt) stage(b ^ 1, (kt + 1) * 64);

        // QK^T: S^T[key 64][q 16]
        const unsigned short* kbb = &Kblob[b][0];
        floatx4 c[4];
#pragma unroll
        for (int g = 0; g < 4; g++) {
            short8 kf0 = *(const short8*)(kbb + (g * 2 + 0) * 512 + lane * 8);
            short8 kf1 = *(const short8*)(kbb + (g * 2 + 1) * 512 + lane * 8);
            floatx4 t = {0.f, 0.f, 0.f, 0.f};
            t = __builtin_amdgcn_mfma_f32_16x16x32_bf16(kf0, aq0, t, 0, 0, 0);
            c[g] = __builtin_amdgcn_mfma_f32_16x16x32_bf16(kf1, aq1, t, 0, 0, 0);
        }

        // softmax over 16 keys/lane (exp2 domain; scores pre-scaled via Q)
        float sv[16];
        if (kb + 63 <= qbase) {  // wave-uniform: whole tile causal-valid
#pragma unroll
            for (int g = 0; g < 4; g++)
#pragma unroll
                for (int r = 0; r < 4; r++) sv[g * 4 + r] = c[g][r];
        } else {
#pragma unroll
            for (int g = 0; g < 4; g++)
#pragma unroll
                for (int r = 0; r < 4; r++) {
                    int key = kb + g * 16 + quad * 4 + r;
                    sv[g * 4 + r] = (key <= qrow) ? c[g][r] : -1e30f;
                }
        }
        float mx = sv[0];
#pragma unroll
        for (int i = 1; i < 16; i++) mx = fmaxf(mx, sv[i]);
        mx = fmaxf(mx, __shfl_xor(mx, 16));
        mx = fmaxf(mx, __shfl_xor(mx, 32));
        float mnew = fmaxf(mv, mx);
        float alpha = exp2f(mv - mnew);
        mv = mnew;
        float p[16], psum = 0.f;
#pragma unroll
        for (int i = 0; i < 16; i++) {
            p[i] = exp2f(sv[i] - mnew);
            psum += p[i];
        }
        lv = lv * alpha + psum;  // per-lane partial; cross-quad reduce at end

        // P -> LDS (row=q l15, key = g*16+quad*4..+3), stride 72 shorts
#pragma unroll
        for (int g = 0; g < 4; g++) {
            uint2 pk;
            pk.x = pack2(p[g * 4 + 0], p[g * 4 + 1]);
            pk.y = pack2(p[g * 4 + 2], p[g * 4 + 3]);
            *(uint2*)(ps + l15 * 72 + g * 16 + quad * 4) = pk;
        }
#pragma unroll
        for (int f = 0; f < 4; f++) {
            o[f][0] *= alpha; o[f][1] *= alpha;
            o[f][2] *= alpha; o[f][3] *= alpha;
        }
        // P^T B-frags (col=q l15, keys quad*8 / +32)
        short8 pf0 = *(const short8*)(ps + l15 * 72 + quad * 8);
        short8 pf1 = *(const short8*)(ps + l15 * 72 + 32 + quad * 8);
        const unsigned short* vbb = &Vblob[b][0];
#pragma unroll
        for (int f = 0; f < 4; f++) {
            short8 vf0 = *(const short8*)(vbb + (f * 2 + 0) * 512 + lane * 8);
            short8 vf1 = *(const short8*)(vbb + (f * 2 + 1) * 512 + lane * 8);
            o[f] = __builtin_amdgcn_mfma_f32_16x16x32_bf16(vf0, pf0, o[f], 0, 0, 0);
            o[f] = __builtin_amdgcn_mfma_f32_16x16x32_bf16(vf1, pf1, o[f], 0, 0, 0);
        }
    }

    // final l reduction across quads, then un-transpose O^T via LDS
    lv += __shfl_xor(lv, 16);
    lv += __shfl_xor(lv, 32);
    float inv = 1.0f / lv;
    __syncthreads();  // safe reuse of Ps region
#pragma unroll
    for (int f = 0; f < 4; f++) {
        uint2 pk;
        pk.x = pack2(o[f][0] * inv, o[f][1] * inv);
        pk.y = pack2(o[f][2] * inv, o[f][3] * inv);
        *(uint2*)(ps + l15 * 72 + f * 16 + quad * 4) = pk;  // row=q, d=f*16+quad*4
    }
    short8 r0 = *(const short8*)(ps + l15 * 72 + quad * 8);
    short8 r1 = *(const short8*)(ps + l15 * 72 + 32 + quad * 8);
    size_t obase = (size_t)(bb * S_LEN + qbase + l15) * DMODEL + h * DK;
    *(short8*)(O + obase + quad * 8) = r0;
    *(short8*)(O + obase + 32 + quad * 8) = r1;
}

// ---------------------------------------------------------------------------
extern "C" void kernel_launch(void* const* d_in, const int* in_sizes, int n_in,
                              void* d_out, int out_size, void* d_ws,
                              size_t ws_size, hipStream_t stream) {
    const float* x = (const float*)d_in[0];
    const float* Wq = (const float*)d_in[1];
    const float* Wk = (const float*)d_in[2];
    const float* Wv = (const float*)d_in[3];
    const float* Wo = (const float*)d_in[4];
    const int* tokpos = (const int*)d_in[5];
    float* out = (float*)d_out;

    const size_t MD = (size_t)MTOT * DMODEL;  // 4194304
    const size_t WD = (size_t)DMODEL * DMODEL;
    unsigned short* xb = (unsigned short*)d_ws;
    unsigned short* Wqt = xb + MD;
    unsigned short* Wkt = Wqt + WD;
    unsigned short* Wvt = Wkt + WD;
    unsigned short* Wot = Wvt + WD;
    unsigned short* Q = Wot + WD;
    unsigned short* K = Q + MD;
    unsigned short* V = K + MD;   // after vtrans, reused as attention output O
    unsigned short* Vt = V + MD;  // [b*1024 + d][s]
    float* ct = (float*)(Vt + MD);
    float* st = ct + S_LEN * 32;
    unsigned short* O = V;  // alias: V dead after vtrans_k

    // fused preprocessing: cast + rope tables + weight transposes
    prep_k<<<dim3(3328), dim3(256), 0, stream>>>(x, xb, tokpos, ct, st,
                                                 Wq, Wk, Wv, Wo, Wqt, Wkt, Wvt, Wot);
    // zero the fp32 output for split-K atomic accumulation (16 MB)
    zero_k<<<dim3(4096), dim3(256), 0, stream>>>(out);

    // Q (RoPE * 0.125/ln2), K (RoPE), V (plain bf16); 256^2 tiles, 8-phase
    mm_k<<<dim3(16, 4, 3), dim3(512), 0, stream>>>(xb, Wqt, Wkt, Wvt,
                                                   (void*)Q, (void*)K, (void*)V, ct, st, 0);
    vtrans_k<<<dim3(64, 16), dim3(256), 0, stream>>>(V, Vt);
    attn_k<<<dim3(512), dim3(512), 0, stream>>>(Q, K, Vt, O);
    // output projection: split-K=4, full-chip 256 blocks, atomic fp32 store
    mm_k<<<dim3(16, 4, 4), dim3(512), 0, stream>>>(O, Wot, Wot, Wot,
                                                   (void*)out, (void*)out, (void*)out, ct, st, 1);
}

// Round 4
// 211.193 us; speedup vs baseline: 1.1480x; 1.1480x over previous
//
#include <hip/hip_runtime.h>
#include <hip/hip_bf16.h>
#include <cmath>

#define S_LEN 2048
#define DMODEL 1024
#define NHEADS 16
#define DK 64
#define BATCH 2
#define MTOT (BATCH * S_LEN) /* 4096 */

using short8 = __attribute__((ext_vector_type(8))) short;
using floatx4 = __attribute__((ext_vector_type(4))) float;

// float -> bf16 bits, round-to-nearest-even (scalar path)
__device__ __forceinline__ unsigned short f2b(float f) {
    union { float f; unsigned u; } v; v.f = f;
    unsigned r = v.u + 0x7fff + ((v.u >> 16) & 1);
    return (unsigned short)(r >> 16);
}

// packed 2x float -> bf16x2 (v_cvt_pk_bf16_f32)
__device__ __forceinline__ unsigned pack2(float a, float b) {
    float2 t; t.x = a; t.y = b;
    __hip_bfloat162 h = __float22bfloat162_rn(t);
    union { __hip_bfloat162 h; unsigned u; } v; v.h = h;
    return v.u;
}

// async global->LDS, 16 B/lane. LDS dest is wave-uniform base (+lane*16 by HW).
__device__ __forceinline__ void gload16(const void* g, void* l) {
    __builtin_amdgcn_global_load_lds(
        (const __attribute__((address_space(1))) unsigned int*)g,
        (__attribute__((address_space(3))) unsigned int*)l, 16, 0, 0);
}

#define FENCE() asm volatile("" ::: "memory")

// ---------------------------------------------------------------------------
// Fused preprocessing (single dispatch, blockIdx-range partition):
//   blocks [0, 2048)        : x fp32 -> bf16 cast
//   blocks [2048, 2304)     : RoPE cos/sin tables
//   blocks [2304, 3328)     : W fp32 [k][n] -> bf16 [n][k] transpose
//                             (Wq,Wk head-dims permuted: d -> d/2 or 32+d/2)
// ---------------------------------------------------------------------------
__global__ __launch_bounds__(256) void prep_k(
    const float* __restrict__ x, unsigned short* __restrict__ xb,
    const int* __restrict__ tokpos, float* __restrict__ ct, float* __restrict__ st,
    const float* W0, const float* W1, const float* W2, const float* W3,
    unsigned short* T0, unsigned short* T1, unsigned short* T2, unsigned short* T3) {
    __shared__ float t[64][65];
    const int b = blockIdx.x;
    if (b < 2048) {
        int i = (b * 256 + threadIdx.x) * 8;
        float4 a = *(const float4*)(x + i);
        float4 bb = *(const float4*)(x + i + 4);
        short8 o;
        o[0] = f2b(a.x); o[1] = f2b(a.y); o[2] = f2b(a.z); o[3] = f2b(a.w);
        o[4] = f2b(bb.x); o[5] = f2b(bb.y); o[6] = f2b(bb.z); o[7] = f2b(bb.w);
        *(short8*)(xb + i) = o;
    } else if (b < 2304) {
        int idx = (b - 2048) * 256 + threadIdx.x;  // 0 .. 2048*32-1
        int si = idx >> 5;
        int ip = idx & 31;
        float pos = (float)tokpos[si];
        float inv_freq = powf(10000.0f, -(float)(2 * ip) / 64.0f);
        float ang = pos * inv_freq;
        ct[idx] = cosf(ang);
        st[idx] = sinf(ang);
    } else {
        int id = b - 2304;          // 0..1023
        int z = id >> 8;            // matrix
        int bx = id & 15, by = (id >> 4) & 15;
        const float* W = z == 0 ? W0 : z == 1 ? W1 : z == 2 ? W2 : W3;
        unsigned short* T = z == 0 ? T0 : z == 1 ? T1 : z == 2 ? T2 : T3;
        const bool perm = (z < 2);
        int n0 = bx * 64, k0 = by * 64;
        int rr = threadIdx.x >> 6, cc = threadIdx.x & 63;
#pragma unroll
        for (int r = 0; r < 16; r++) {
            int row = r * 4 + rr;
            t[row][cc] = W[(size_t)(k0 + row) * DMODEL + n0 + cc];
        }
        __syncthreads();
#pragma unroll
        for (int r = 0; r < 16; r++) {
            int row = r * 4 + rr;  // original col within head
            int drow = perm ? (((row & 1) ? 32 : 0) + (row >> 1)) : row;
            T[(size_t)(n0 + drow) * DMODEL + k0 + cc] = f2b(t[cc][row]);
        }
    }
}

// ---------------------------------------------------------------------------
// out += P1 (split-K reduce): 2048 blocks x 256 thr x 8 floats, 48 MB traffic
// ---------------------------------------------------------------------------
__global__ __launch_bounds__(256) void add_k(float* __restrict__ out,
                                             const float* __restrict__ p) {
    int i = (blockIdx.x * 256 + threadIdx.x) * 8;
    float4 a = *(const float4*)(out + i);
    float4 b = *(const float4*)(p + i);
    float4 c = *(const float4*)(out + i + 4);
    float4 d = *(const float4*)(p + i + 4);
    a.x += b.x; a.y += b.y; a.z += b.z; a.w += b.w;
    c.x += d.x; c.y += d.y; c.z += d.z; c.w += d.w;
    *(float4*)(out + i) = a;
    *(float4*)(out + i + 4) = c;
}

// ---------------------------------------------------------------------------
// V[s][d] bf16 -> Vt[b*1024 + d][s] bf16, 64x64 LDS tiles
// ---------------------------------------------------------------------------
__global__ __launch_bounds__(256) void vtrans_k(const unsigned short* __restrict__ V,
                                                unsigned short* __restrict__ Vt) {
    __shared__ unsigned short t[64][72];  // 144 B rows: 16B-aligned, bank-spread
    const int tid = threadIdx.x;
    const int s0 = blockIdx.x * 64, d0 = blockIdx.y * 64;
    const int bb = s0 >> 11;
#pragma unroll
    for (int it = 0; it < 4; it++) {
        int e = (it * 256 + tid) * 4;  // flat ushort4 id: row=s, col=d
        int r = e >> 6, c = e & 63;
        *(ushort4*)&t[r][c] = *(const ushort4*)(V + (size_t)(s0 + r) * DMODEL + d0 + c);
    }
    __syncthreads();
#pragma unroll
    for (int it = 0; it < 4; it++) {
        int e = (it * 256 + tid) * 4;  // flat ushort4 id: row=d, col=s
        int r = e >> 6, c = e & 63;
        ushort4 v;
        v.x = t[c + 0][r]; v.y = t[c + 1][r];
        v.z = t[c + 2][r]; v.w = t[c + 3][r];
        *(ushort4*)(Vt + (size_t)(bb * 1024 + d0 + r) * S_LEN + (s0 & (S_LEN - 1)) + c) = v;
    }
}

// ---------------------------------------------------------------------------
// bf16 MFMA GEMM, 256x256 tile, BK=64, 8 waves (2M x 4N), 8-phase schedule
// with COUNTED vmcnt (T3+T4) + setprio (T5).
// K-range parameterized (t0, NT K-tiles) for split-K.
//   kind 0: z selects matrix (Q/K/V), full K (t0=0, NT=16). RoPE/bf16
//     epilogues as before.
//   kind 1 (Wo): split-K=2, z = K-half (t0=8z, NT=8), grid (16,4,2)=128
//     blocks; PLAIN coalesced fp32 stores (z=0 -> out, z=1 -> partial P1;
//     add_k reduces). R3's atomicAdd epilogue was the regression: 64 MB of
//     4B atomics at ~1 TB/s effective = ~50 us of the 62 us dispatch.
// Rotation/vmcnt invariants hold for any NT>=3: prologue 6 halves ->
// vmcnt(4) leaves h4,h5 in flight; per-K-tile vmcnt(4); drain-0 at t==NT-2.
// ---------------------------------------------------------------------------
__global__ __launch_bounds__(512, 2) void mm_k(
    const unsigned short* __restrict__ A,
    const unsigned short* __restrict__ Bt0, const unsigned short* __restrict__ Bt1,
    const unsigned short* __restrict__ Bt2,
    void* C0, void* C1, void* C2,
    const float* __restrict__ ct, const float* __restrict__ st, int kind) {
    __shared__ __align__(16) unsigned short blob[10 * 8192];  // 160 KiB

    const int z = blockIdx.z;
    const unsigned short* Bt = (kind == 1) ? Bt0 : (z == 0 ? Bt0 : z == 1 ? Bt1 : Bt2);
    void* C = (kind == 1) ? (z == 0 ? C0 : C1) : (z == 0 ? C0 : z == 1 ? C1 : C2);
    const int mode = (kind == 1) ? 0 : (z == 2 ? 3 : 1);
    const int t0 = (kind == 1) ? z * 8 : 0;   // starting K-tile
    const int NT = (kind == 1) ? 8 : 16;      // K-tiles this block
    // 0.125/ln2: QK^T scaling + exp2-domain softmax, folded into Q
    const float qscale = (z == 0 && kind == 0) ? 0.18033688011112042f : 1.0f;

    const int tid = threadIdx.x;
    const int w = tid >> 6, lane = tid & 63;
    const int l15 = lane & 15, quad = lane >> 4;
    const int wr = w >> 2, wc = w & 3;  // 2 x 4 waves; per-wave out 128x64
    const int m0 = blockIdx.x * 256, n0 = blockIdx.y * 256;  // x=m: XCD A-reuse

    // staging: per half-tile (16KB = 16 groups of 1KB), wave w owns groups
    // {w, w+8}: rows rbase / rbase+64 of the 128-row half, k-half (w&1).
    const int rbase = (w >> 1) * 16 + l15;
    const int cbase = (w & 1) * 32 + quad * 8;

    floatx4 acc[8][4];
#pragma unroll
    for (int i = 0; i < 8; i++)
#pragma unroll
        for (int j = 0; j < 4; j++) acc[i][j] = (floatx4){0.f, 0.f, 0.f, 0.f};

    auto stage_half = [&](int h) {   // h relative: K-tile t0 + (h>>2)
        const int ts = t0 + (h >> 2), part = h & 3;
        const int slot = h % 10;
        const unsigned short* src =
            (part < 2 ? A + (((size_t)(m0 + part * 128 + rbase)) << 10)
                      : Bt + (((size_t)(n0 + (part - 2) * 128 + rbase)) << 10))
            + (size_t)ts * 64 + cbase;
        char* d = (char*)blob + slot * 16384 + w * 1024;
        gload16(src, d);                       // group w   (rows rbase)
        gload16(src + (64 << 10), d + 8192);   // group w+8 (rows rbase+64)
    };

    // prologue: 6 half-tiles issued; vmcnt(4) -> K-tile t0 (h0..3) landed,
    // h4,h5 still in flight.
#pragma unroll
    for (int h = 0; h < 6; ++h) stage_half(h);
    asm volatile("s_waitcnt vmcnt(4)" ::: "memory");
    FENCE(); __builtin_amdgcn_s_barrier(); FENCE();

    short8 af[4][2];
    for (int t = 0; t < NT; ++t) {
        const int sb = (4 * t) % 10;
        int sA = sb + wr;            if (sA >= 10) sA -= 10;
        int sB = sb + 2 + (wc >> 1); if (sB >= 10) sB -= 10;
        const char* LA = (const char*)blob + sA * 16384;
        const char* LB = (const char*)blob + sB * 16384;
#pragma unroll
        for (int q = 0; q < 4; ++q) {
            const int rh = q >> 1, ch = q & 1;
            if (ch == 0) {  // A-frags for this row-half (reused next phase)
#pragma unroll
                for (int ii = 0; ii < 4; ++ii)
#pragma unroll
                    for (int kh = 0; kh < 2; ++kh)
                        af[ii][kh] = *(const short8*)(LA + ((rh * 4 + ii) * 2 + kh) * 1024 + lane * 16);
            }
            short8 bf[2][2];
#pragma unroll
            for (int jj = 0; jj < 2; ++jj)
#pragma unroll
                for (int kh = 0; kh < 2; ++kh)
                    bf[jj][kh] = *(const short8*)(LB + (((wc & 1) * 4 + ch * 2 + jj) * 2 + kh) * 1024 + lane * 16);
            const int h = 4 * t + q + 6;
            if (h < 4 * NT) stage_half(h);
            if (q == 3) {
                if (t == NT - 2) asm volatile("s_waitcnt vmcnt(0)" ::: "memory");  // tail drain
                else             asm volatile("s_waitcnt vmcnt(4)" ::: "memory");  // counted
            }
            FENCE(); __builtin_amdgcn_s_barrier(); FENCE();
            __builtin_amdgcn_s_setprio(1);
#pragma unroll
            for (int ii = 0; ii < 4; ++ii)
#pragma unroll
                for (int jj = 0; jj < 2; ++jj) {
                    floatx4 a0 = acc[rh * 4 + ii][ch * 2 + jj];
                    a0 = __builtin_amdgcn_mfma_f32_16x16x32_bf16(af[ii][0], bf[jj][0], a0, 0, 0, 0);
                    a0 = __builtin_amdgcn_mfma_f32_16x16x32_bf16(af[ii][1], bf[jj][1], a0, 0, 0, 0);
                    acc[rh * 4 + ii][ch * 2 + jj] = a0;
                }
            __builtin_amdgcn_s_setprio(0);
            FENCE(); __builtin_amdgcn_s_barrier(); FENCE();
        }
    }

    // epilogue: C/D layout col = l15, row = quad*4 + reg
#pragma unroll
    for (int i = 0; i < 8; i++) {
        const int rowb = m0 + wr * 128 + i * 16 + quad * 4;
        if (mode == 0) {
            float* Cf = (float*)C;
#pragma unroll
            for (int j = 0; j < 4; j++) {
                int colb = n0 + wc * 64 + j * 16 + l15;
#pragma unroll
                for (int r = 0; r < 4; r++)
                    Cf[(size_t)(rowb + r) * DMODEL + colb] = acc[i][j][r];
            }
        } else if (mode == 1) {
            unsigned short* Cb = (unsigned short*)C;
#pragma unroll
            for (int jh = 0; jh < 2; jh++) {
                int ip = jh * 16 + l15;                   // pair index within head
                int cole = n0 + wc * 64 + jh * 16 + l15;  // even-member column (d'<32)
#pragma unroll
                for (int r = 0; r < 4; r++) {
                    int row = rowb + r;
                    int si = row & (S_LEN - 1);
                    float c = ct[si * 32 + ip] * qscale;
                    float s = st[si * 32 + ip] * qscale;
                    float e = acc[i][jh][r];       // x_even (permuted weights)
                    float od = acc[i][jh + 2][r];  // x_odd (partner col, same thread)
                    Cb[(size_t)row * DMODEL + cole] = f2b(e * c - od * s);
                    Cb[(size_t)row * DMODEL + cole + 32] = f2b(e * s + od * c);
                }
            }
        } else {
            unsigned short* Cb = (unsigned short*)C;
#pragma unroll
            for (int j = 0; j < 4; j++) {
                int colb = n0 + wc * 64 + j * 16 + l15;
#pragma unroll
                for (int r = 0; r < 4; r++)
                    Cb[(size_t)(rowb + r) * DMODEL + colb] = f2b(acc[i][j][r]);
            }
        }
    }
}

// ---------------------------------------------------------------------------
// Block-cooperative MFMA flash attention, 64-key tiles, 128-query blocks.
// R1 structure (grid 512 longest-first, __syncthreads double-buffer) with
// bit-exact VALU cuts re-applied from R2 (whose regression was the dispatch
// order, not these): tree-max, wave-uniform alpha-skip (alpha==1 exactly),
// skip of fully-masked final tile for waves 0-3 (exact zeros; barriers
// untouched), setprio around MFMA clusters.
// ---------------------------------------------------------------------------
__global__ __launch_bounds__(512) void attn_k(const unsigned short* __restrict__ Q,
                                              const unsigned short* __restrict__ K,
                                              const unsigned short* __restrict__ Vt,
                                              unsigned short* __restrict__ O) {
    __shared__ __align__(16) unsigned short Kblob[2][4096];  // 8 KB/buf
    __shared__ __align__(16) unsigned short Vblob[2][4096];
    __shared__ __align__(16) unsigned short Ps[8][16 * 72];  // per-wave P / O-bounce

    const int tid = threadIdx.x;
    const int w = tid >> 6, lane = tid & 63;
    const int l15 = lane & 15, quad = lane >> 4;
    const int idx = blockIdx.x;
    const int qt = 15 - (idx >> 5);  // longest blocks dispatch first
    const int bh = idx & 31;
    const int bb = bh >> 4, h = bh & 15;
    const int qbase = qt * 128 + w * 16;
    const int qrow = qbase + l15;

    // Q fragment (B-operand: col=query=l15, k=quad*8), d-halves 0/1
    const size_t qoff = (size_t)(bb * S_LEN + qbase + l15) * DMODEL + h * DK;
    short8 aq0 = *(const short8*)(Q + qoff + quad * 8);
    short8 aq1 = *(const short8*)(Q + qoff + 32 + quad * 8);

    floatx4 o[4];
#pragma unroll
    for (int f = 0; f < 4; f++) o[f] = (floatx4){0.f, 0.f, 0.f, 0.f};
    float mv = -1e30f, lv = 0.f;

    const unsigned short* Kb = K + (size_t)(bb * S_LEN) * DMODEL + h * DK;
    const unsigned short* Vb = Vt + (size_t)(bb * 1024 + h * DK) * S_LEN;
    unsigned short* ps = &Ps[w][0];

    // stage 64-key K/V tile into blob buffer b (2 gload16/thread, 8 waves)
    auto stage = [&](int b, int kb) {
#pragma unroll
        for (int it = 0; it < 2; it++) {
            int g = it * 8 + w;  // wave-uniform 0..15; 0..7 K-groups, 8..15 V-groups
            if (g < 8) {
                const unsigned short* gp =
                    Kb + (size_t)(kb + (g >> 1) * 16 + l15) * DMODEL + (g & 1) * 32 + quad * 8;
                gload16(gp, (char*)&Kblob[b][0] + g * 1024);
            } else {
                int gv = g - 8;
                const unsigned short* gp =
                    Vb + (size_t)((gv >> 1) * 16 + l15) * S_LEN + kb + (gv & 1) * 32 + quad * 8;
                gload16(gp, (char*)&Vblob[b][0] + gv * 1024);
            }
        }
    };

    const int nkt = 2 * qt + 2;  // key tiles covering 0..qt*128+127, uniform
    stage(0, 0);
    for (int kt = 0; kt < nkt; kt++) {
        const int b = kt & 1;
        const int kb = kt * 64;
        __syncthreads();  // staging of buf b complete; buf b^1 reads done
        if (kt + 1 < nkt) stage(b ^ 1, (kt + 1) * 64);

        // waves 0-3 skip the final (fully causal-masked) tile: exact zeros.
        if (kb <= qbase + 15) {
            // QK^T: S^T[key 64][q 16]
            const unsigned short* kbb = &Kblob[b][0];
            floatx4 c[4];
            __builtin_amdgcn_s_setprio(1);
#pragma unroll
            for (int g = 0; g < 4; g++) {
                short8 kf0 = *(const short8*)(kbb + (g * 2 + 0) * 512 + lane * 8);
                short8 kf1 = *(const short8*)(kbb + (g * 2 + 1) * 512 + lane * 8);
                floatx4 t = {0.f, 0.f, 0.f, 0.f};
                t = __builtin_amdgcn_mfma_f32_16x16x32_bf16(kf0, aq0, t, 0, 0, 0);
                c[g] = __builtin_amdgcn_mfma_f32_16x16x32_bf16(kf1, aq1, t, 0, 0, 0);
            }
            __builtin_amdgcn_s_setprio(0);

            // softmax over 16 keys/lane (exp2 domain; scores pre-scaled via Q)
            float sv[16];
            if (kb + 63 <= qbase) {  // wave-uniform: whole tile causal-valid
#pragma unroll
                for (int g = 0; g < 4; g++)
#pragma unroll
                    for (int r = 0; r < 4; r++) sv[g * 4 + r] = c[g][r];
            } else {
#pragma unroll
                for (int g = 0; g < 4; g++)
#pragma unroll
                    for (int r = 0; r < 4; r++) {
                        int key = kb + g * 16 + quad * 4 + r;
                        sv[g * 4 + r] = (key <= qrow) ? c[g][r] : -1e30f;
                    }
            }
            // tree max (v_max3-friendly, depth 4; fmax is exact/assoc)
            float t0 = fmaxf(fmaxf(sv[0], sv[1]), sv[2]);
            float t1 = fmaxf(fmaxf(sv[3], sv[4]), sv[5]);
            float t2 = fmaxf(fmaxf(sv[6], sv[7]), sv[8]);
            float t3 = fmaxf(fmaxf(sv[9], sv[10]), sv[11]);
            float t4 = fmaxf(fmaxf(sv[12], sv[13]), sv[14]);
            float mx = fmaxf(fmaxf(fmaxf(t0, t1), fmaxf(t2, t3)), fmaxf(t4, sv[15]));
            mx = fmaxf(mx, __shfl_xor(mx, 16));
            mx = fmaxf(mx, __shfl_xor(mx, 32));

            // wave-uniform rescale skip: if no query's max grew, alpha==1
            // exactly -> skipping the muls + exp2 is bit-exact.
            if (!__all(mx <= mv)) {
                float mnew = fmaxf(mv, mx);
                float alpha = exp2f(mv - mnew);
                mv = mnew;
                lv *= alpha;
#pragma unroll
                for (int f = 0; f < 4; f++) {
                    o[f][0] *= alpha; o[f][1] *= alpha;
                    o[f][2] *= alpha; o[f][3] *= alpha;
                }
            }
            float p[16], psum = 0.f;
#pragma unroll
            for (int i = 0; i < 16; i++) {
                p[i] = exp2f(sv[i] - mv);
                psum += p[i];
            }
            lv += psum;  // == lv*alpha + psum of the original form

            // P -> LDS (row=q l15, key = g*16+quad*4..+3), stride 72 shorts
#pragma unroll
            for (int g = 0; g < 4; g++) {
                uint2 pk;
                pk.x = pack2(p[g * 4 + 0], p[g * 4 + 1]);
                pk.y = pack2(p[g * 4 + 2], p[g * 4 + 3]);
                *(uint2*)(ps + l15 * 72 + g * 16 + quad * 4) = pk;
            }
            // P^T B-frags (col=q l15, keys quad*8 / +32)
            short8 pf0 = *(const short8*)(ps + l15 * 72 + quad * 8);
            short8 pf1 = *(const short8*)(ps + l15 * 72 + 32 + quad * 8);
            const unsigned short* vbb = &Vblob[b][0];
            __builtin_amdgcn_s_setprio(1);
#pragma unroll
            for (int f = 0; f < 4; f++) {
                short8 vf0 = *(const short8*)(vbb + (f * 2 + 0) * 512 + lane * 8);
                short8 vf1 = *(const short8*)(vbb + (f * 2 + 1) * 512 + lane * 8);
                o[f] = __builtin_amdgcn_mfma_f32_16x16x32_bf16(vf0, pf0, o[f], 0, 0, 0);
                o[f] = __builtin_amdgcn_mfma_f32_16x16x32_bf16(vf1, pf1, o[f], 0, 0, 0);
            }
            __builtin_amdgcn_s_setprio(0);
        }
    }

    // final l reduction across quads, then un-transpose O^T via LDS
    lv += __shfl_xor(lv, 16);
    lv += __shfl_xor(lv, 32);
    float inv = 1.0f / lv;
    __syncthreads();  // safe reuse of Ps region
#pragma unroll
    for (int f = 0; f < 4; f++) {
        uint2 pk;
        pk.x = pack2(o[f][0] * inv, o[f][1] * inv);
        pk.y = pack2(o[f][2] * inv, o[f][3] * inv);
        *(uint2*)(ps + l15 * 72 + f * 16 + quad * 4) = pk;  // row=q, d=f*16+quad*4
    }
    short8 r0 = *(const short8*)(ps + l15 * 72 + quad * 8);
    short8 r1 = *(const short8*)(ps + l15 * 72 + 32 + quad * 8);
    size_t obase = (size_t)(bb * S_LEN + qbase + l15) * DMODEL + h * DK;
    *(short8*)(O + obase + quad * 8) = r0;
    *(short8*)(O + obase + 32 + quad * 8) = r1;
}

// ---------------------------------------------------------------------------
extern "C" void kernel_launch(void* const* d_in, const int* in_sizes, int n_in,
                              void* d_out, int out_size, void* d_ws,
                              size_t ws_size, hipStream_t stream) {
    const float* x = (const float*)d_in[0];
    const float* Wq = (const float*)d_in[1];
    const float* Wk = (const float*)d_in[2];
    const float* Wv = (const float*)d_in[3];
    const float* Wo = (const float*)d_in[4];
    const int* tokpos = (const int*)d_in[5];
    float* out = (float*)d_out;

    const size_t MD = (size_t)MTOT * DMODEL;  // 4194304
    const size_t WD = (size_t)DMODEL * DMODEL;
    unsigned short* xb = (unsigned short*)d_ws;
    unsigned short* Wqt = xb + MD;
    unsigned short* Wkt = Wqt + WD;
    unsigned short* Wvt = Wkt + WD;
    unsigned short* Wot = Wvt + WD;
    unsigned short* Q = Wot + WD;
    unsigned short* K = Q + MD;
    unsigned short* V = K + MD;   // after vtrans, reused as attention output O
    unsigned short* Vt = V + MD;  // [b*1024 + d][s]
    float* ct = (float*)(Vt + MD);
    float* st = ct + S_LEN * 32;
    unsigned short* O = V;  // alias: V dead after vtrans_k
    // split-K partial: 16 MB fp32 over the dead Q+K regions (Q,K unread
    // after attn_k; Wo mm reads only O (=V region) and Wot).
    float* P1 = (float*)Q;

    // fused preprocessing: cast + rope tables + weight transposes
    prep_k<<<dim3(3328), dim3(256), 0, stream>>>(x, xb, tokpos, ct, st,
                                                 Wq, Wk, Wv, Wo, Wqt, Wkt, Wvt, Wot);

    // Q (RoPE * 0.125/ln2), K (RoPE), V (plain bf16); 256^2 tiles, 8-phase
    mm_k<<<dim3(16, 4, 3), dim3(512), 0, stream>>>(xb, Wqt, Wkt, Wvt,
                                                   (void*)Q, (void*)K, (void*)V, ct, st, 0);
    vtrans_k<<<dim3(64, 16), dim3(256), 0, stream>>>(V, Vt);
    attn_k<<<dim3(512), dim3(512), 0, stream>>>(Q, K, Vt, O);
    // output projection: split-K=2 (128 blocks), plain fp32 stores, reduce
    mm_k<<<dim3(16, 4, 2), dim3(512), 0, stream>>>(O, Wot, Wot, Wot,
                                                   (void*)out, (void*)P1, (void*)P1, ct, st, 1);
    add_k<<<dim3(2048), dim3(256), 0, stream>>>(out, P1);
}